// Round 8
// baseline (259.836 us; speedup 1.0000x reference)
//
#include <hip/hip_runtime.h>
#include <stdint.h>

typedef __attribute__((ext_vector_type(4))) float f32x4;
typedef __attribute__((ext_vector_type(8))) __bf16 bf16x8;

// ---- fixed problem geometry ----
constexpr int MS_[3] = {2000, 6000, 4000};
constexpr int MP_[3] = {2048, 6144, 4096};
constexpr int RB_[3] = {32, 96, 64};        // 64-row tiles (prep/epi)
constexpr int NTILE = 192;
constexpr long long OUT_OFF_[3] = {16, 512016, 2048016};

// pass-1: BM=64, BN=32, split-K S1 per d
constexpr int S1_[3] = {8, 16, 16};
constexpr int KS1_[3] = {256, 384, 256};    // Mp / S1
constexpr int NG1 = 1536 + 1024 + 256;      // d1,d2,d0 = 2816 (%8==0)
// pass-2: BM=64, BN=128, S2=4
constexpr int KS2_[3] = {512, 1536, 1024};
constexpr int NG2 = 384 + 256 + 128;        // 768 (%8==0)
// conv grid
constexpr int NCONV = 2304 + 1024 + 256;    // 3584

__device__ __forceinline__ unsigned short f2bf(float f) {
  __bf16 b = (__bf16)f;
  return *reinterpret_cast<unsigned short*>(&b);
}

__device__ __forceinline__ void gload_lds16(const void* g, void* l) {
  __builtin_amdgcn_global_load_lds(
      (const __attribute__((address_space(1))) unsigned int*)g,
      (__attribute__((address_space(3))) unsigned int*)l, 16, 0, 0);
}

__device__ __forceinline__ void bar_pin() {
  __builtin_amdgcn_s_barrier();
  __builtin_amdgcn_sched_barrier(0);
}

template <int W>
__device__ __forceinline__ void wait_w() {
  if constexpr (W == 0) asm volatile("s_waitcnt vmcnt(0)" ::: "memory");
  else if constexpr (W == 5) asm volatile("s_waitcnt vmcnt(5)" ::: "memory");
  else if constexpr (W == 6) asm volatile("s_waitcnt vmcnt(6)" ::: "memory");
}

// chunked XCD swizzle (requires nwg % 8 == 0): each XCD gets a contiguous
// range of logical block ids -> B-panel L2 locality per XCD.
__device__ __forceinline__ int xcd_swz(int bid, int nwg) {
  int cpx = nwg >> 3;
  return (bid & 7) * cpx + (bid >> 3);
}

__device__ __forceinline__ void tile_decode(int bid, int& d, int& t) {
  if (bid < RB_[0]) { d = 0; t = bid; }
  else if (bid < RB_[0] + RB_[1]) { d = 1; t = bid - RB_[0]; }
  else { d = 2; t = bid - RB_[0] - RB_[1]; }
}

// =====================================================================
// conv: Lb = bf16(L). 8-deep unrolled float4-granular stream (the R7
// version had VGPR=8 -> 1 load in flight -> latency-bound at 3.4 TB/s).
// =====================================================================
struct ConvArgs {
  const float* src[3];
  unsigned short* dst[3];
};

__global__ __launch_bounds__(256) void conv_k(ConvArgs ca) {
  int bid = blockIdx.x;
  int d, lb, nb;
  if (bid < 2304) { d = 1; lb = bid; nb = 2304; }
  else if (bid < 3328) { d = 2; lb = bid - 2304; nb = 1024; }
  else { d = 0; lb = bid - 3328; nb = 256; }
  const float* __restrict__ s = ca.src[d];
  unsigned short* __restrict__ o = ca.dst[d];
  const long long n4 = (long long)MS_[d] * MS_[d] / 4;  // float4 units
  const long long stride = (long long)nb * 2048;        // 256 thr * 8 units
  for (long long base = (long long)lb * 2048 + threadIdx.x; base < n4; base += stride) {
    long long c[8];
    f32x4 v[8];
#pragma unroll
    for (int k = 0; k < 8; ++k) {
      c[k] = base + k * 256;
      v[k] = (c[k] < n4) ? *reinterpret_cast<const f32x4*>(s + c[k] * 4)
                         : (f32x4){0.f, 0.f, 0.f, 0.f};
    }
#pragma unroll
    for (int k = 0; k < 8; ++k) {
      if (c[k] < n4) {
        union { unsigned short u[4]; int2 q; } pk;
#pragma unroll
        for (int j = 0; j < 4; ++j) pk.u[j] = f2bf(v[k][j]);
        *reinterpret_cast<int2*>(o + c[k] * 4) = pk.q;
      }
    }
  }
}

// =====================================================================
// prep: xT[c][m] = bf16(x[b][i][m]) zero-padded to Mp; zero colsum bufs
// =====================================================================
struct PrepArgs {
  const float* x[3];
  unsigned short* xT[3];
  float* zero0; int zero_n;
};

__global__ __launch_bounds__(256) void prep_k(PrepArgs pa) {
  int d, t; tile_decode(blockIdx.x, d, t);
  const int M = MS_[d], Mp = MP_[d];
  const float* x = pa.x[d];
  unsigned short* xT = pa.xT[d];
  const int tid = threadIdx.x;
  const int m0 = t * 64;
  const int ml = tid & 63, cg = tid >> 6;
  const int m = m0 + ml;
  const bool valid = m < M;
#pragma unroll
  for (int it = 0; it < 8; ++it) {
    int c = it * 4 + cg;
    float v = valid ? x[(size_t)c * M + m] : 0.f;
    xT[(size_t)c * Mp + m] = f2bf(v);
  }
  if (blockIdx.x == 0) {
    for (int i = tid; i < pa.zero_n; i += 256) pa.zero0[i] = 0.f;
  }
}

// =====================================================================
// GEMM (both passes): P[s][Mp][PW] partials of L @ Bt^T.
// A from bf16 Lb (L3-resident). All staging via global_load_lds; ring
// buffers; exact counted vmcnt; s_barrier + sched_barrier(0) pin.
//   p1: 3 ops/step, ring4 -> 9 in flight, W=6. waves 4x1 (16 rows each).
//   p2: 6 ops/step, ring3 -> 12 in flight, W=6. waves 2x2 (32r x 64c)
//       -> per-wave LDS reads 18 -> 12 (minimal 2x redundancy).
// =====================================================================
struct GArgs {
  const float* L[3];
  const unsigned short* Lb[3];
  const unsigned short* B[3];
  float* P[3];
};

template <int PASS>
__global__ __launch_bounds__(256, (PASS == 1) ? 3 : 2) void gemm_k(GArgs ga) {
  int bid = xcd_swz(blockIdx.x, (PASS == 1) ? NG1 : NG2);
  int d, r, s;
  if constexpr (PASS == 1) {  // longest-first: d1, d2, d0
    if (bid < 1536) { d = 1; r = bid % 96; s = bid / 96; }
    else if (bid < 2560) { bid -= 1536; d = 2; r = bid % 64; s = bid / 64; }
    else { bid -= 2560; d = 0; r = bid % 32; s = bid / 32; }
  } else {
    if (bid < 384) { d = 1; r = bid % 96; s = bid / 96; }
    else if (bid < 640) { bid -= 384; d = 2; r = bid % 64; s = bid / 64; }
    else { bid -= 640; d = 0; r = bid % 32; s = bid / 32; }
  }
  const int M = MS_[d], Mp = MP_[d];
  const int KS = (PASS == 1) ? KS1_[d] : KS2_[d];
  const int ns = KS >> 6;
  constexpr int BN = (PASS == 1) ? 32 : 128;
  constexpr int PW = BN;
  constexpr int NR = BN / 16;
  constexpr int BIB = BN / 32;                 // B ops/thread/step
  constexpr int RING = (PASS == 1) ? 4 : 3;
  constexpr int W = 6;

  const unsigned short* __restrict__ Bt = ga.B[d];
  float* __restrict__ Pp = ga.P[d];

  const int m0 = r * 64;
  const int kt0 = s * KS;

  __shared__ __align__(16) char Al[RING][8192];
  __shared__ __align__(16) char Bl[RING][BN * 128];

  const int tid = threadIdx.x;
  const int lane = tid & 63;
  const int wave = tid >> 6;
  const int lr = lane & 15, lk = lane >> 4;
  const int wr = wave >> 1, wc = wave & 1;   // pass-2 wave grid

  // --- A staging descriptors (pre-swizzled source, bf16) ---
  const char* rowA[2];
  int koffA[2];
#pragma unroll
  for (int j = 0; j < 2; ++j) {
    int ldsb = j * 4096 + tid * 16;
    int row = ldsb >> 7;
    int inner = (ldsb & 127) ^ ((row & 7) << 4);
    int grow = m0 + row;
    if (grow > M - 1) grow = M - 1;  // garbage rows masked downstream
    rowA[j] = (const char*)(ga.Lb[d] + (size_t)grow * M);
    koffA[j] = inner >> 1;  // bf16 elems
  }
  // --- B staging descriptors (pre-swizzled source) ---
  const unsigned short* srcB[BIB];
#pragma unroll
  for (int j = 0; j < BIB; ++j) {
    int ldsb = j * 4096 + tid * 16;
    int col = ldsb >> 7;
    int inner = (ldsb & 127) ^ ((col & 7) << 4);
    srcB[j] = Bt + (size_t)col * Mp + (inner >> 1);
  }

  f32x4 acc[NR];
#pragma unroll
  for (int n = 0; n < NR; ++n) acc[n] = (f32x4){0.f, 0.f, 0.f, 0.f};

  auto mstep = [&](int x) { return x < ns ? x : ns - 1; };
  auto stage = [&](int slot, int step) {
    const int kt = kt0 + step * 64;
#pragma unroll
    for (int j = 0; j < 2; ++j) {
      int gk = kt + koffA[j];
      if (gk + 8 > M) gk = 0;  // pad region: B is zero there -> product 0
      gload_lds16(rowA[j] + (size_t)gk * 2, &Al[slot][j * 4096 + tid * 16]);
    }
#pragma unroll
    for (int j = 0; j < BIB; ++j)
      gload_lds16(srcB[j] + kt, &Bl[slot][j * 4096 + tid * 16]);
  };

  auto readA = [&](const char* Ab, int rowl) -> bf16x8 {
    // rowl encodes row*8 + k-quarter index packed by caller via byte math
    return *reinterpret_cast<const bf16x8*>(Ab + rowl);
  };

  auto compute = [&](int slot) {
    const char* Ab = &Al[slot][0];
    const char* Bb = &Bl[slot][0];
    if constexpr (PASS == 1) {
      const int rowl = wave * 16 + lr;
      const int base = rowl * 128, swz = (rowl & 7) << 4;
      bf16x8 af0 = readA(Ab, base + ((lk * 16) ^ swz));
      bf16x8 af1 = readA(Ab, base + ((64 + lk * 16) ^ swz));
#pragma unroll
      for (int nr = 0; nr < NR; ++nr) {
        const int col = nr * 16 + lr;
        const int bbase = col * 128, bswz = (col & 7) << 4;
        bf16x8 b0 = *reinterpret_cast<const bf16x8*>(Bb + bbase + ((lk * 16) ^ bswz));
        bf16x8 b1 = *reinterpret_cast<const bf16x8*>(Bb + bbase + ((64 + lk * 16) ^ bswz));
        acc[nr] = __builtin_amdgcn_mfma_f32_16x16x32_bf16(af0, b0, acc[nr], 0, 0, 0);
        acc[nr] = __builtin_amdgcn_mfma_f32_16x16x32_bf16(af1, b1, acc[nr], 0, 0, 0);
      }
    } else {
      // 2x2 wave grid: wave owns rows wr*32..+31, cols wc*64..+63
      bf16x8 af[2][2];
#pragma unroll
      for (int mr = 0; mr < 2; ++mr) {
        const int rowl = wr * 32 + mr * 16 + lr;
        const int base = rowl * 128, swz = (rowl & 7) << 4;
        af[mr][0] = readA(Ab, base + ((lk * 16) ^ swz));
        af[mr][1] = readA(Ab, base + ((64 + lk * 16) ^ swz));
      }
#pragma unroll
      for (int nr = 0; nr < 4; ++nr) {
        const int col = wc * 64 + nr * 16 + lr;
        const int bbase = col * 128, bswz = (col & 7) << 4;
        bf16x8 b0 = *reinterpret_cast<const bf16x8*>(Bb + bbase + ((lk * 16) ^ bswz));
        bf16x8 b1 = *reinterpret_cast<const bf16x8*>(Bb + bbase + ((64 + lk * 16) ^ bswz));
#pragma unroll
        for (int mr = 0; mr < 2; ++mr) {
          acc[mr * 4 + nr] = __builtin_amdgcn_mfma_f32_16x16x32_bf16(af[mr][0], b0, acc[mr * 4 + nr], 0, 0, 0);
          acc[mr * 4 + nr] = __builtin_amdgcn_mfma_f32_16x16x32_bf16(af[mr][1], b1, acc[mr * 4 + nr], 0, 0, 0);
        }
      }
    }
  };

  // prologue: fill RING-1 buffers
  stage(0, 0);
  stage(1, mstep(1));
  if constexpr (RING >= 4) stage(2, mstep(2));

  for (int t = 0; t < ns; ++t) {
    wait_w<W>();   // drains exactly the oldest staged step
    bar_pin();
    stage((t + RING - 1) % RING, mstep(t + RING - 1));
    compute(t % RING);
  }

  // epilogue: per-split partials (no atomics)
  if constexpr (PASS == 1) {
    const int rowb = m0 + wave * 16 + lk * 4;
#pragma unroll
    for (int nr = 0; nr < NR; ++nr) {
      const int cc = nr * 16 + lr;
#pragma unroll
      for (int j = 0; j < 4; ++j)
        Pp[((size_t)s * Mp + rowb + j) * PW + cc] = acc[nr][j];
    }
  } else {
#pragma unroll
    for (int mr = 0; mr < 2; ++mr) {
      const int rowb = m0 + wr * 32 + mr * 16 + lk * 4;
#pragma unroll
      for (int nr = 0; nr < 4; ++nr) {
        const int cc = wc * 64 + nr * 16 + lr;
#pragma unroll
        for (int j = 0; j < 4; ++j)
          Pp[((size_t)s * Mp + rowb + j) * PW + cc] = acc[mr * 4 + nr][j];
      }
    }
  }
}

// =====================================================================
// epiA: z = leaky(bias + th0*x + th1*Y1) -> bf16 zT (sums S1_[d] partials)
// =====================================================================
struct EpiAArgs {
  const float* part1[3];
  const float* x[3];
  const float* th1[3];
  const float* b1[3];
  unsigned short* zT[3];
};

__global__ __launch_bounds__(256) void epiA_k(EpiAArgs ea) {
  int d, t; tile_decode(blockIdx.x, d, t);
  const int M = MS_[d], Mp = MP_[d];
  const int m0 = t * 64;
  __shared__ float Ys[32 * 66];
  __shared__ float Xs[32 * 66];
  const int tid = threadIdx.x;
  const float* part = ea.part1[d];
  const size_t st = (size_t)Mp * 32;
  const int S1 = S1_[d];
#pragma unroll
  for (int it = 0; it < 8; ++it) {
    int idx = it * 256 + tid;
    int m = idx >> 5, c = idx & 31;
    size_t base = (size_t)(m0 + m) * 32 + c;
    float ssum = 0.f;
    for (int s5 = 0; s5 < S1; ++s5) ssum += part[s5 * st + base];
    Ys[c * 66 + m] = ssum;
  }
  {
    const float* x = ea.x[d];
    int m = tid & 63, cg = tid >> 6;
    bool valid = (m0 + m) < M;
#pragma unroll
    for (int it = 0; it < 8; ++it) {
      int c = it * 4 + cg;
      Xs[c * 66 + m] = valid ? x[(size_t)c * M + m0 + m] : 0.f;
    }
  }
  __syncthreads();
  const float* th = ea.th1[d];
  const float* bias = ea.b1[d];
  unsigned short* zT = ea.zT[d];
  const int m = tid & 63, cog = tid >> 6;
  const bool valid = (m0 + m) < M;
#pragma unroll
  for (int it = 0; it < 32; ++it) {
    int co = it * 4 + cog;
    int o = co & 15, b = co >> 4;
    float a = bias[o];
#pragma unroll
    for (int i = 0; i < 4; ++i) {
      int ci = b * 4 + i;
      a += th[(o * 4 + i) * 2] * Xs[ci * 66 + m] + th[(o * 4 + i) * 2 + 1] * Ys[ci * 66 + m];
    }
    float zz = (a >= 0.f) ? a : 0.01f * a;
    zT[(size_t)co * Mp + m0 + m] = valid ? f2bf(zz) : (unsigned short)0;
  }
}

// =====================================================================
// epiB: out2 = th2_0 * z + th2_1 * Y2 ; column-sums for pooled means
// =====================================================================
struct EpiBArgs {
  const float* part2[3];
  const unsigned short* zT[3];
  const float* th2[3];
  float* out;
  float* csz;
  float* csy;
};

__global__ __launch_bounds__(256) void epiB_k(EpiBArgs eb) {
  int d, t; tile_decode(blockIdx.x, d, t);
  const int M = MS_[d], Mp = MP_[d];
  const int m0 = t * 64;
  __shared__ float Ys[128 * 66];
  __shared__ float red[256];
  const int tid = threadIdx.x;
  const float* part = eb.part2[d];
  float csum = 0.f;
#pragma unroll
  for (int it = 0; it < 32; ++it) {
    int idx = it * 256 + tid;
    int m = idx >> 7, c = idx & 127;
    size_t base = (size_t)(m0 + m) * 128 + c;
    size_t st = (size_t)Mp * 128;
    float ssum = part[base] + part[st + base] + part[2 * st + base] + part[3 * st + base];
    Ys[c * 66 + m] = ssum;
    if (m0 + m < M) csum += ssum;
  }
  red[tid] = csum;
  __syncthreads();
  if (tid < 128) atomicAdd(&eb.csy[d * 128 + tid], red[tid] + red[tid + 128]);

  const unsigned short* zT = eb.zT[d];
  const float* th = eb.th2[d];
  float* outp = eb.out + OUT_OFF_[d];
  const int m = tid & 63, g = tid >> 6;
  const bool valid = (m0 + m) < M;
#pragma unroll
  for (int bb = 0; bb < 2; ++bb) {
    int b = g * 2 + bb;
    float zv[16], yv[16];
#pragma unroll
    for (int o1 = 0; o1 < 16; ++o1) {
      int c = b * 16 + o1;
      unsigned short raw = zT[(size_t)c * Mp + m0 + m];
      __bf16 bf = *reinterpret_cast<__bf16*>(&raw);
      zv[o1] = (float)bf;
      yv[o1] = Ys[c * 66 + m];
    }
#pragma unroll
    for (int o1 = 0; o1 < 16; ++o1) {
      float v = zv[o1];
#pragma unroll
      for (int off = 32; off > 0; off >>= 1) v += __shfl_xor(v, off, 64);
      if (m == 0) atomicAdd(&eb.csz[d * 128 + b * 16 + o1], v);
    }
#pragma unroll
    for (int o2 = 0; o2 < 32; ++o2) {
      float v = 0.f;
#pragma unroll
      for (int o1 = 0; o1 < 16; ++o1)
        v += th[(o2 * 16 + o1) * 2] * zv[o1] + th[(o2 * 16 + o1) * 2 + 1] * yv[o1];
      if (valid) outp[(size_t)(b * 32 + o2) * M + m0 + m] = v;
    }
  }
}

// =====================================================================
// MLP: pooled from colsums, then 4 affine layers -> logits
// =====================================================================
struct MlpArgs {
  const float* csz; const float* csy;
  const float* th2[3];
  const float* W1; const float* b1;
  const float* W2; const float* b2;
  const float* W3; const float* b3;
  const float* W4; const float* b4;
  float* out;
};

__global__ __launch_bounds__(256) void mlp_k(MlpArgs ma) {
  __shared__ float pl[8][96];
  __shared__ float h1[8][64];
  __shared__ float h2[8][32];
  __shared__ float h3[8][16];
  const int tid = threadIdx.x;
  for (int id = tid; id < 768; id += 256) {
    int d = id >> 8, rem = id & 255, b = rem >> 5, o2 = rem & 31;
    const float* th = ma.th2[d];
    float invM = 1.f / (float)MS_[d];
    float v = 0.f;
    for (int o1 = 0; o1 < 16; ++o1)
      v += th[(o2 * 16 + o1) * 2] * ma.csz[d * 128 + b * 16 + o1] +
           th[(o2 * 16 + o1) * 2 + 1] * ma.csy[d * 128 + b * 16 + o1];
    pl[b][d * 32 + o2] = v * invM;
  }
  __syncthreads();
  for (int id = tid; id < 512; id += 256) {
    int b = id >> 6, j = id & 63;
    float v = ma.b1[j];
    for (int k = 0; k < 96; ++k) v += pl[b][k] * ma.W1[j * 96 + k];
    h1[b][j] = v;
  }
  __syncthreads();
  {
    int b = tid >> 5, j = tid & 31;
    float v = ma.b2[j];
    for (int k = 0; k < 64; ++k) v += h1[b][k] * ma.W2[j * 64 + k];
    h2[b][j] = v;
  }
  __syncthreads();
  if (tid < 128) {
    int b = tid >> 4, j = tid & 15;
    float v = ma.b3[j];
    for (int k = 0; k < 32; ++k) v += h2[b][k] * ma.W3[j * 32 + k];
    h3[b][j] = v;
  }
  __syncthreads();
  if (tid < 16) {
    int b = tid >> 1, j = tid & 1;
    float v = ma.b4[j];
    for (int k = 0; k < 16; ++k) v += h3[b][k] * ma.W4[j * 16 + k];
    ma.out[tid] = v;
  }
}

// =====================================================================
extern "C" void kernel_launch(void* const* d_in, const int* in_sizes, int n_in,
                              void* d_out, int out_size, void* d_ws, size_t ws_size,
                              hipStream_t stream) {
  (void)in_sizes; (void)n_in; (void)out_size; (void)ws_size;
  const float* L[3]   = {(const float*)d_in[0], (const float*)d_in[5], (const float*)d_in[10]};
  const float* x[3]   = {(const float*)d_in[1], (const float*)d_in[6], (const float*)d_in[11]};
  const float* th1[3] = {(const float*)d_in[2], (const float*)d_in[7], (const float*)d_in[12]};
  const float* b1[3]  = {(const float*)d_in[3], (const float*)d_in[8], (const float*)d_in[13]};
  const float* th2[3] = {(const float*)d_in[4], (const float*)d_in[9], (const float*)d_in[14]};
  const float* W1 = (const float*)d_in[15]; const float* bb1 = (const float*)d_in[16];
  const float* W2 = (const float*)d_in[17]; const float* bb2 = (const float*)d_in[18];
  const float* W3 = (const float*)d_in[19]; const float* bb3 = (const float*)d_in[20];
  const float* W4 = (const float*)d_in[21]; const float* bb4 = (const float*)d_in[22];
  float* out = (float*)d_out;

  char* ws = (char*)d_ws;
  size_t off = 0;
  auto alloc = [&](size_t bytes) {
    size_t r = off;
    off = (off + bytes + 255) & ~(size_t)255;
    return r;
  };
  const int MPs[3] = {2048, 6144, 4096};
  unsigned short* xT[3]; unsigned short* zT[3]; float* pb[3];
  for (int d = 0; d < 3; ++d) xT[d] = (unsigned short*)(ws + alloc((size_t)32 * MPs[d] * 2));
  for (int d = 0; d < 3; ++d) zT[d] = (unsigned short*)(ws + alloc((size_t)128 * MPs[d] * 2));
  for (int d = 0; d < 3; ++d) pb[d] = (float*)(ws + alloc((size_t)16 * MPs[d] * 32 * 4));
  float* csz = (float*)(ws + alloc((size_t)3 * 128 * 4));
  float* csy = (float*)(ws + alloc((size_t)3 * 128 * 4));
  unsigned short* Lb[3];
  for (int d = 0; d < 3; ++d)
    Lb[d] = (unsigned short*)(ws + alloc((size_t)MS_[d] * MS_[d] * 2));

  PrepArgs pa;
  for (int d = 0; d < 3; ++d) { pa.x[d] = x[d]; pa.xT[d] = xT[d]; }
  pa.zero0 = csz; pa.zero_n = 768;
  prep_k<<<NTILE, 256, 0, stream>>>(pa);

  ConvArgs ca;
  for (int d = 0; d < 3; ++d) { ca.src[d] = L[d]; ca.dst[d] = Lb[d]; }
  conv_k<<<NCONV, 256, 0, stream>>>(ca);

  GArgs ga;
  for (int d = 0; d < 3; ++d) {
    ga.L[d] = L[d]; ga.Lb[d] = Lb[d]; ga.P[d] = pb[d];
  }

  for (int d = 0; d < 3; ++d) ga.B[d] = xT[d];
  gemm_k<1><<<NG1, 256, 0, stream>>>(ga);

  EpiAArgs ea;
  for (int d = 0; d < 3; ++d) {
    ea.part1[d] = pb[d]; ea.x[d] = x[d]; ea.th1[d] = th1[d]; ea.b1[d] = b1[d]; ea.zT[d] = zT[d];
  }
  epiA_k<<<NTILE, 256, 0, stream>>>(ea);

  for (int d = 0; d < 3; ++d) ga.B[d] = zT[d];
  gemm_k<2><<<NG2, 256, 0, stream>>>(ga);

  EpiBArgs eb;
  for (int d = 0; d < 3; ++d) { eb.part2[d] = pb[d]; eb.zT[d] = zT[d]; eb.th2[d] = th2[d]; }
  eb.out = out; eb.csz = csz; eb.csy = csy;
  epiB_k<<<NTILE, 256, 0, stream>>>(eb);

  MlpArgs ma;
  ma.csz = csz; ma.csy = csy;
  for (int d = 0; d < 3; ++d) ma.th2[d] = th2[d];
  ma.W1 = W1; ma.b1 = bb1; ma.W2 = W2; ma.b2 = bb2;
  ma.W3 = W3; ma.b3 = bb3; ma.W4 = W4; ma.b4 = bb4;
  ma.out = out;
  mlp_k<<<1, 256, 0, stream>>>(ma);
}

// Round 9
// 233.846 us; speedup vs baseline: 1.1111x; 1.1111x over previous
//
#include <hip/hip_runtime.h>
#include <stdint.h>

typedef __attribute__((ext_vector_type(4))) float f32x4;
typedef __attribute__((ext_vector_type(8))) __bf16 bf16x8;

// ---- fixed problem geometry ----
constexpr int MS_[3] = {2000, 6000, 4000};
constexpr int MP_[3] = {2048, 6144, 4096};
constexpr int RB_[3] = {32, 96, 64};        // 64-row tiles (prep/epi)
constexpr int NTILE = 192;
constexpr long long OUT_OFF_[3] = {16, 512016, 2048016};

// pass-1: BM=64, BN=32, split-K S1=4 -> long blocks (ns = 8/24/16)
constexpr int KS1_[3] = {512, 1536, 1024};  // Mp / 4
constexpr int NG1 = 384 + 256 + 128;        // d1,d2,d0 = 768 (%8==0)
// pass-2: BM=64, BN=64 (2 col halves), S2=2 -> ns = 16/48/32
constexpr int KS2_[3] = {1024, 3072, 2048}; // Mp / 2
constexpr int NG2 = 384 + 256 + 128;        // 768 (%8==0)

__device__ __forceinline__ unsigned short f2bf(float f) {
  __bf16 b = (__bf16)f;
  return *reinterpret_cast<unsigned short*>(&b);
}

__device__ __forceinline__ void gload_lds16(const void* g, void* l) {
  __builtin_amdgcn_global_load_lds(
      (const __attribute__((address_space(1))) unsigned int*)g,
      (__attribute__((address_space(3))) unsigned int*)l, 16, 0, 0);
}

__device__ __forceinline__ void bar_pin() {
  __builtin_amdgcn_s_barrier();
  __builtin_amdgcn_sched_barrier(0);
}

template <int W>
__device__ __forceinline__ void wait_w() {
  if constexpr (W == 6)  asm volatile("s_waitcnt vmcnt(6)" ::: "memory");
  else if constexpr (W == 10) asm volatile("s_waitcnt vmcnt(10)" ::: "memory");
  else asm volatile("s_waitcnt vmcnt(0)" ::: "memory");
}

// chunked XCD swizzle (requires nwg % 8 == 0)
__device__ __forceinline__ int xcd_swz(int bid, int nwg) {
  int cpx = nwg >> 3;
  return (bid & 7) * cpx + (bid >> 3);
}

__device__ __forceinline__ void tile_decode(int bid, int& d, int& t) {
  if (bid < RB_[0]) { d = 0; t = bid; }
  else if (bid < RB_[0] + RB_[1]) { d = 1; t = bid - RB_[0]; }
  else { d = 2; t = bid - RB_[0] - RB_[1]; }
}

// =====================================================================
// prep: xT[c][m] = bf16(x[b][i][m]) zero-padded to Mp; zero colsum bufs
// =====================================================================
struct PrepArgs {
  const float* x[3];
  unsigned short* xT[3];
  float* zero0; int zero_n;
};

__global__ __launch_bounds__(256) void prep_k(PrepArgs pa) {
  int d, t; tile_decode(blockIdx.x, d, t);
  const int M = MS_[d], Mp = MP_[d];
  const float* x = pa.x[d];
  unsigned short* xT = pa.xT[d];
  const int tid = threadIdx.x;
  const int m0 = t * 64;
  const int ml = tid & 63, cg = tid >> 6;
  const int m = m0 + ml;
  const bool valid = m < M;
#pragma unroll
  for (int it = 0; it < 8; ++it) {
    int c = it * 4 + cg;
    float v = valid ? x[(size_t)c * M + m] : 0.f;
    xT[(size_t)c * Mp + m] = f2bf(v);
  }
  if (blockIdx.x == 0) {
    for (int i = tid; i < pa.zero_n; i += 256) pa.zero0[i] = 0.f;
  }
}

// =====================================================================
// GEMM (both passes): P[s][Mp][PW] partials of L @ Bt^T. A = f32 L (no
// conversion pass), all staging via global_load_lds, LONG blocks so the
// pipeline-fill prologue amortizes (R4/R6 had ns=2-6 -> 40-60% fill cost).
//   p1: 5 ops/step (A4+B1), ring4 (80KB), W=10, ns=8/24/16.
//   p2: 6 ops/step (A4+B2), ring3 (72KB), W=6,  ns=16/48/32, 2x2 waves.
// =====================================================================
struct GArgs {
  const float* L[3];
  const unsigned short* B[3];
  float* P[3];
};

template <int PASS>
__global__ __launch_bounds__(256, 2) void gemm_k(GArgs ga) {
  int bid = xcd_swz(blockIdx.x, (PASS == 1) ? NG1 : NG2);
  int d, r, s, nh = 0;
  if constexpr (PASS == 1) {  // longest-first: d1, d2, d0
    if (bid < 384) { d = 1; r = bid % 96; s = bid / 96; }
    else if (bid < 640) { bid -= 384; d = 2; r = bid % 64; s = bid / 64; }
    else { bid -= 640; d = 0; r = bid % 32; s = bid / 32; }
  } else {
    if (bid < 384) { d = 1; r = bid % 96; int q = bid / 96; nh = q & 1; s = q >> 1; }
    else if (bid < 640) { bid -= 384; d = 2; r = bid % 64; int q = bid / 64; nh = q & 1; s = q >> 1; }
    else { bid -= 640; d = 0; r = bid % 32; int q = bid / 32; nh = q & 1; s = q >> 1; }
  }
  const int M = MS_[d], Mp = MP_[d];
  const int KS = (PASS == 1) ? KS1_[d] : KS2_[d];
  const int ns = KS >> 6;
  constexpr int BN = (PASS == 1) ? 32 : 64;
  constexpr int PW = (PASS == 1) ? 32 : 128;
  constexpr int BIB = BN / 32;                 // B ops/thread/step
  constexpr int RING = (PASS == 1) ? 4 : 3;
  constexpr int W = (PASS == 1) ? 10 : 6;

  const float* __restrict__ Lp = ga.L[d];
  const unsigned short* __restrict__ Bt = ga.B[d];
  float* __restrict__ Pp = ga.P[d];

  const int m0 = r * 64;
  const int kt0 = s * KS;

  __shared__ __align__(16) char Al[RING][16384];     // f32 A tile 64x64
  __shared__ __align__(16) char Bl[RING][BN * 128];  // bf16 B tile

  const int tid = threadIdx.x;
  const int lane = tid & 63;
  const int wave = tid >> 6;
  const int lr = lane & 15, lk = lane >> 4;
  const int wr = wave >> 1, wc = wave & 1;   // pass-2 wave grid

  // --- A staging descriptors: 4 x 16B per thread, pre-swizzled f32 source ---
  const float* rowA[4];
  int koffA[4];
#pragma unroll
  for (int j = 0; j < 4; ++j) {
    int ldsb = j * 4096 + tid * 16;
    int row = ldsb >> 8;
    int inner = (ldsb & 255) ^ ((row & 7) << 5);   // 32B-granular XOR swizzle
    int grow = m0 + row;
    if (grow > M - 1) grow = M - 1;  // garbage rows masked downstream
    rowA[j] = Lp + (size_t)grow * M;
    koffA[j] = inner >> 2;  // f32 elems
  }
  // --- B staging descriptors (pre-swizzled source) ---
  const unsigned short* srcB[BIB];
#pragma unroll
  for (int j = 0; j < BIB; ++j) {
    int ldsb = j * 4096 + tid * 16;
    int col = ldsb >> 7;
    int inner = (ldsb & 127) ^ ((col & 7) << 4);   // 16B-granular XOR swizzle
    srcB[j] = Bt + (size_t)(nh * 64 + col) * Mp + (inner >> 1);
  }

  constexpr int NACC = (PASS == 1) ? 2 : 4;
  f32x4 acc[NACC];
#pragma unroll
  for (int n = 0; n < NACC; ++n) acc[n] = (f32x4){0.f, 0.f, 0.f, 0.f};

  auto mstep = [&](int x) { return x < ns ? x : ns - 1; };
  auto stage = [&](int slot, int step) {
    const int kt = kt0 + step * 64;
#pragma unroll
    for (int j = 0; j < 4; ++j) {
      int gk = kt + koffA[j];
      if (gk + 4 > M) gk = 0;  // pad: B zero there -> product 0
      gload_lds16(rowA[j] + gk, &Al[slot][j * 4096 + tid * 16]);
    }
#pragma unroll
    for (int j = 0; j < BIB; ++j)
      gload_lds16(srcB[j] + kt, &Bl[slot][j * 4096 + tid * 16]);
  };

  auto readAf = [&](const char* Ab, int rowl, int kk) -> bf16x8 {
    const int base = rowl * 256, swz = (rowl & 7) << 5;
    int off = base + ((kk * 128 + lk * 32) ^ swz);
    f32x4 v0 = *reinterpret_cast<const f32x4*>(Ab + off);
    f32x4 v1 = *reinterpret_cast<const f32x4*>(Ab + off + 16);
    bf16x8 af;
#pragma unroll
    for (int j = 0; j < 4; ++j) { af[j] = (__bf16)v0[j]; af[4 + j] = (__bf16)v1[j]; }
    return af;
  };
  auto readB = [&](const char* Bb, int col, int half) -> bf16x8 {
    const int bbase = col * 128, bswz = (col & 7) << 4;
    return *reinterpret_cast<const bf16x8*>(Bb + bbase + ((half * 64 + lk * 16) ^ bswz));
  };

  auto compute = [&](int slot) {
    const char* Ab = &Al[slot][0];
    const char* Bb = &Bl[slot][0];
    if constexpr (PASS == 1) {
      const int rowl = wave * 16 + lr;
      bf16x8 a0 = readAf(Ab, rowl, 0), a1 = readAf(Ab, rowl, 1);
#pragma unroll
      for (int nr = 0; nr < 2; ++nr) {
        bf16x8 b0 = readB(Bb, nr * 16 + lr, 0);
        bf16x8 b1 = readB(Bb, nr * 16 + lr, 1);
        acc[nr] = __builtin_amdgcn_mfma_f32_16x16x32_bf16(a0, b0, acc[nr], 0, 0, 0);
        acc[nr] = __builtin_amdgcn_mfma_f32_16x16x32_bf16(a1, b1, acc[nr], 0, 0, 0);
      }
    } else {
      // 2x2 wave grid: rows wr*32..+31, cols wc*32..+31
      bf16x8 af[2][2];
#pragma unroll
      for (int mr = 0; mr < 2; ++mr) {
        af[mr][0] = readAf(Ab, wr * 32 + mr * 16 + lr, 0);
        af[mr][1] = readAf(Ab, wr * 32 + mr * 16 + lr, 1);
      }
#pragma unroll
      for (int nr = 0; nr < 2; ++nr) {
        const int col = wc * 32 + nr * 16 + lr;
        bf16x8 b0 = readB(Bb, col, 0);
        bf16x8 b1 = readB(Bb, col, 1);
#pragma unroll
        for (int mr = 0; mr < 2; ++mr) {
          acc[mr * 2 + nr] = __builtin_amdgcn_mfma_f32_16x16x32_bf16(af[mr][0], b0, acc[mr * 2 + nr], 0, 0, 0);
          acc[mr * 2 + nr] = __builtin_amdgcn_mfma_f32_16x16x32_bf16(af[mr][1], b1, acc[mr * 2 + nr], 0, 0, 0);
        }
      }
    }
  };

  // prologue: fill RING-1 buffers
  stage(0, 0);
  stage(1, mstep(1));
  if constexpr (RING >= 4) stage(2, mstep(2));

  for (int t = 0; t < ns; ++t) {
    wait_w<W>();   // drains exactly the oldest staged step, never to 0
    bar_pin();
    stage((t + RING - 1) % RING, mstep(t + RING - 1));
    compute(t % RING);
  }

  // epilogue: per-split partials (no atomics)
  if constexpr (PASS == 1) {
    const int rowb = m0 + wave * 16 + lk * 4;
#pragma unroll
    for (int nr = 0; nr < 2; ++nr) {
      const int cc = nr * 16 + lr;
#pragma unroll
      for (int j = 0; j < 4; ++j)
        Pp[((size_t)s * Mp + rowb + j) * PW + cc] = acc[nr][j];
    }
  } else {
#pragma unroll
    for (int mr = 0; mr < 2; ++mr) {
      const int rowb = m0 + wr * 32 + mr * 16 + lk * 4;
#pragma unroll
      for (int nr = 0; nr < 2; ++nr) {
        const int cc = nh * 64 + wc * 32 + nr * 16 + lr;
#pragma unroll
        for (int j = 0; j < 4; ++j)
          Pp[((size_t)s * Mp + rowb + j) * PW + cc] = acc[mr * 2 + nr][j];
      }
    }
  }
}

// =====================================================================
// epiA: z = leaky(bias + th0*x + th1*Y1) -> bf16 zT (sums 4 partials)
// =====================================================================
struct EpiAArgs {
  const float* part1[3];
  const float* x[3];
  const float* th1[3];
  const float* b1[3];
  unsigned short* zT[3];
};

__global__ __launch_bounds__(256) void epiA_k(EpiAArgs ea) {
  int d, t; tile_decode(blockIdx.x, d, t);
  const int M = MS_[d], Mp = MP_[d];
  const int m0 = t * 64;
  __shared__ float Ys[32 * 66];
  __shared__ float Xs[32 * 66];
  const int tid = threadIdx.x;
  const float* part = ea.part1[d];
  const size_t st = (size_t)Mp * 32;
#pragma unroll
  for (int it = 0; it < 8; ++it) {
    int idx = it * 256 + tid;
    int m = idx >> 5, c = idx & 31;
    size_t base = (size_t)(m0 + m) * 32 + c;
    float ssum = part[base] + part[st + base] + part[2 * st + base] + part[3 * st + base];
    Ys[c * 66 + m] = ssum;
  }
  {
    const float* x = ea.x[d];
    int m = tid & 63, cg = tid >> 6;
    bool valid = (m0 + m) < M;
#pragma unroll
    for (int it = 0; it < 8; ++it) {
      int c = it * 4 + cg;
      Xs[c * 66 + m] = valid ? x[(size_t)c * M + m0 + m] : 0.f;
    }
  }
  __syncthreads();
  const float* th = ea.th1[d];
  const float* bias = ea.b1[d];
  unsigned short* zT = ea.zT[d];
  const int m = tid & 63, cog = tid >> 6;
  const bool valid = (m0 + m) < M;
#pragma unroll
  for (int it = 0; it < 32; ++it) {
    int co = it * 4 + cog;
    int o = co & 15, b = co >> 4;
    float a = bias[o];
#pragma unroll
    for (int i = 0; i < 4; ++i) {
      int ci = b * 4 + i;
      a += th[(o * 4 + i) * 2] * Xs[ci * 66 + m] + th[(o * 4 + i) * 2 + 1] * Ys[ci * 66 + m];
    }
    float zz = (a >= 0.f) ? a : 0.01f * a;
    zT[(size_t)co * Mp + m0 + m] = valid ? f2bf(zz) : (unsigned short)0;
  }
}

// =====================================================================
// epiB: out2 = th2_0 * z + th2_1 * Y2 ; column-sums for pooled means
// (pass-2 has S2=2 partials)
// =====================================================================
struct EpiBArgs {
  const float* part2[3];
  const unsigned short* zT[3];
  const float* th2[3];
  float* out;
  float* csz;
  float* csy;
};

__global__ __launch_bounds__(256) void epiB_k(EpiBArgs eb) {
  int d, t; tile_decode(blockIdx.x, d, t);
  const int M = MS_[d], Mp = MP_[d];
  const int m0 = t * 64;
  __shared__ float Ys[128 * 66];
  __shared__ float red[256];
  const int tid = threadIdx.x;
  const float* part = eb.part2[d];
  float csum = 0.f;
#pragma unroll
  for (int it = 0; it < 32; ++it) {
    int idx = it * 256 + tid;
    int m = idx >> 7, c = idx & 127;
    size_t base = (size_t)(m0 + m) * 128 + c;
    size_t st = (size_t)Mp * 128;
    float ssum = part[base] + part[st + base];
    Ys[c * 66 + m] = ssum;
    if (m0 + m < M) csum += ssum;
  }
  red[tid] = csum;
  __syncthreads();
  if (tid < 128) atomicAdd(&eb.csy[d * 128 + tid], red[tid] + red[tid + 128]);

  const unsigned short* zT = eb.zT[d];
  const float* th = eb.th2[d];
  float* outp = eb.out + OUT_OFF_[d];
  const int m = tid & 63, g = tid >> 6;
  const bool valid = (m0 + m) < M;
#pragma unroll
  for (int bb = 0; bb < 2; ++bb) {
    int b = g * 2 + bb;
    float zv[16], yv[16];
#pragma unroll
    for (int o1 = 0; o1 < 16; ++o1) {
      int c = b * 16 + o1;
      unsigned short raw = zT[(size_t)c * Mp + m0 + m];
      __bf16 bf = *reinterpret_cast<__bf16*>(&raw);
      zv[o1] = (float)bf;
      yv[o1] = Ys[c * 66 + m];
    }
#pragma unroll
    for (int o1 = 0; o1 < 16; ++o1) {
      float v = zv[o1];
#pragma unroll
      for (int off = 32; off > 0; off >>= 1) v += __shfl_xor(v, off, 64);
      if (m == 0) atomicAdd(&eb.csz[d * 128 + b * 16 + o1], v);
    }
#pragma unroll
    for (int o2 = 0; o2 < 32; ++o2) {
      float v = 0.f;
#pragma unroll
      for (int o1 = 0; o1 < 16; ++o1)
        v += th[(o2 * 16 + o1) * 2] * zv[o1] + th[(o2 * 16 + o1) * 2 + 1] * yv[o1];
      if (valid) outp[(size_t)(b * 32 + o2) * M + m0 + m] = v;
    }
  }
}

// =====================================================================
// MLP: pooled from colsums, then 4 affine layers -> logits
// =====================================================================
struct MlpArgs {
  const float* csz; const float* csy;
  const float* th2[3];
  const float* W1; const float* b1;
  const float* W2; const float* b2;
  const float* W3; const float* b3;
  const float* W4; const float* b4;
  float* out;
};

__global__ __launch_bounds__(256) void mlp_k(MlpArgs ma) {
  __shared__ float pl[8][96];
  __shared__ float h1[8][64];
  __shared__ float h2[8][32];
  __shared__ float h3[8][16];
  const int tid = threadIdx.x;
  for (int id = tid; id < 768; id += 256) {
    int d = id >> 8, rem = id & 255, b = rem >> 5, o2 = rem & 31;
    const float* th = ma.th2[d];
    float invM = 1.f / (float)MS_[d];
    float v = 0.f;
    for (int o1 = 0; o1 < 16; ++o1)
      v += th[(o2 * 16 + o1) * 2] * ma.csz[d * 128 + b * 16 + o1] +
           th[(o2 * 16 + o1) * 2 + 1] * ma.csy[d * 128 + b * 16 + o1];
    pl[b][d * 32 + o2] = v * invM;
  }
  __syncthreads();
  for (int id = tid; id < 512; id += 256) {
    int b = id >> 6, j = id & 63;
    float v = ma.b1[j];
    for (int k = 0; k < 96; ++k) v += pl[b][k] * ma.W1[j * 96 + k];
    h1[b][j] = v;
  }
  __syncthreads();
  {
    int b = tid >> 5, j = tid & 31;
    float v = ma.b2[j];
    for (int k = 0; k < 64; ++k) v += h1[b][k] * ma.W2[j * 64 + k];
    h2[b][j] = v;
  }
  __syncthreads();
  if (tid < 128) {
    int b = tid >> 4, j = tid & 15;
    float v = ma.b3[j];
    for (int k = 0; k < 32; ++k) v += h2[b][k] * ma.W3[j * 32 + k];
    h3[b][j] = v;
  }
  __syncthreads();
  if (tid < 16) {
    int b = tid >> 1, j = tid & 1;
    float v = ma.b4[j];
    for (int k = 0; k < 16; ++k) v += h3[b][k] * ma.W4[j * 16 + k];
    ma.out[tid] = v;
  }
}

// =====================================================================
extern "C" void kernel_launch(void* const* d_in, const int* in_sizes, int n_in,
                              void* d_out, int out_size, void* d_ws, size_t ws_size,
                              hipStream_t stream) {
  (void)in_sizes; (void)n_in; (void)out_size; (void)ws_size;
  const float* L[3]   = {(const float*)d_in[0], (const float*)d_in[5], (const float*)d_in[10]};
  const float* x[3]   = {(const float*)d_in[1], (const float*)d_in[6], (const float*)d_in[11]};
  const float* th1[3] = {(const float*)d_in[2], (const float*)d_in[7], (const float*)d_in[12]};
  const float* b1[3]  = {(const float*)d_in[3], (const float*)d_in[8], (const float*)d_in[13]};
  const float* th2[3] = {(const float*)d_in[4], (const float*)d_in[9], (const float*)d_in[14]};
  const float* W1 = (const float*)d_in[15]; const float* bb1 = (const float*)d_in[16];
  const float* W2 = (const float*)d_in[17]; const float* bb2 = (const float*)d_in[18];
  const float* W3 = (const float*)d_in[19]; const float* bb3 = (const float*)d_in[20];
  const float* W4 = (const float*)d_in[21]; const float* bb4 = (const float*)d_in[22];
  float* out = (float*)d_out;

  char* ws = (char*)d_ws;
  size_t off = 0;
  auto alloc = [&](size_t bytes) {
    size_t r = off;
    off = (off + bytes + 255) & ~(size_t)255;
    return r;
  };
  const int MPs[3] = {2048, 6144, 4096};
  unsigned short* xT[3]; unsigned short* zT[3]; float* pb[3];
  for (int d = 0; d < 3; ++d) xT[d] = (unsigned short*)(ws + alloc((size_t)32 * MPs[d] * 2));
  for (int d = 0; d < 3; ++d) zT[d] = (unsigned short*)(ws + alloc((size_t)128 * MPs[d] * 2));
  // pass-1 partials: 4 x Mp x 32 f32 = 512*Mp B; pass-2: 2 x Mp x 128 f32 =
  // 1024*Mp B. Overlaid (disjoint lifetimes); alloc the max.
  for (int d = 0; d < 3; ++d) pb[d] = (float*)(ws + alloc((size_t)MPs[d] * 1024));
  float* csz = (float*)(ws + alloc((size_t)3 * 128 * 4));
  float* csy = (float*)(ws + alloc((size_t)3 * 128 * 4));

  PrepArgs pa;
  for (int d = 0; d < 3; ++d) { pa.x[d] = x[d]; pa.xT[d] = xT[d]; }
  pa.zero0 = csz; pa.zero_n = 768;
  prep_k<<<NTILE, 256, 0, stream>>>(pa);

  GArgs ga;
  for (int d = 0; d < 3; ++d) { ga.L[d] = L[d]; ga.P[d] = pb[d]; }

  for (int d = 0; d < 3; ++d) ga.B[d] = xT[d];
  gemm_k<1><<<NG1, 256, 0, stream>>>(ga);

  EpiAArgs ea;
  for (int d = 0; d < 3; ++d) {
    ea.part1[d] = pb[d]; ea.x[d] = x[d]; ea.th1[d] = th1[d]; ea.b1[d] = b1[d]; ea.zT[d] = zT[d];
  }
  epiA_k<<<NTILE, 256, 0, stream>>>(ea);

  for (int d = 0; d < 3; ++d) ga.B[d] = zT[d];
  gemm_k<2><<<NG2, 256, 0, stream>>>(ga);

  EpiBArgs eb;
  for (int d = 0; d < 3; ++d) { eb.part2[d] = pb[d]; eb.zT[d] = zT[d]; eb.th2[d] = th2[d]; }
  eb.out = out; eb.csz = csz; eb.csy = csy;
  epiB_k<<<NTILE, 256, 0, stream>>>(eb);

  MlpArgs ma;
  ma.csz = csz; ma.csy = csy;
  for (int d = 0; d < 3; ++d) ma.th2[d] = th2[d];
  ma.W1 = W1; ma.b1 = bb1; ma.W2 = W2; ma.b2 = bb2;
  ma.W3 = W3; ma.b3 = bb3; ma.W4 = W4; ma.b4 = bb4;
  ma.out = out;
  mlp_k<<<1, 256, 0, stream>>>(ma);
}

// Round 10
// 192.807 us; speedup vs baseline: 1.3476x; 1.2128x over previous
//
#include <hip/hip_runtime.h>
#include <stdint.h>

typedef __attribute__((ext_vector_type(4))) float f32x4;
typedef __attribute__((ext_vector_type(8))) __bf16 bf16x8;

// ---- fixed problem geometry (from setup_inputs) ----
constexpr int MS_[3] = {2000, 6000, 4000};
constexpr int MP_[3] = {2048, 6144, 4096};  // = 8*KS1 = 4*KS2 exactly
constexpr int RB_[3] = {32, 96, 64};        // row blocks of 64 (Mp/64)
constexpr int NTILE = 192;                  // sum RB
constexpr long long OUT_OFF_[3] = {16, 512016, 2048016};

// pass-1: BM=64, BN=32, S=8  -> ns = {4,12,8}
constexpr int KS1_[3] = {256, 768, 512};
constexpr int NB1_[3] = {256, 768, 512};    // RB*8
constexpr int NG1 = 1536;                   // %8==0
// pass-2: BM=64, BN=128, S=4 -> ns = {8,24,16}
constexpr int KS2_[3] = {512, 1536, 1024};
constexpr int NB2_[3] = {128, 384, 256};    // RB*4
constexpr int NG2 = 768;                    // %8==0

__device__ __forceinline__ unsigned short f2bf(float f) {
  __bf16 b = (__bf16)f;
  return *reinterpret_cast<unsigned short*>(&b);
}

__device__ __forceinline__ void gload_lds16(const void* g, void* l) {
  __builtin_amdgcn_global_load_lds(
      (const __attribute__((address_space(1))) unsigned int*)g,
      (__attribute__((address_space(3))) unsigned int*)l, 16, 0, 0);
}

template <int BN>
__device__ __forceinline__ void wait_main() {
  if constexpr (BN == 128) asm volatile("s_waitcnt vmcnt(12)" ::: "memory");
  else                     asm volatile("s_waitcnt vmcnt(6)" ::: "memory");
}
template <int BN>
__device__ __forceinline__ void wait_tail() {
  if constexpr (BN == 128) asm volatile("s_waitcnt vmcnt(8)" ::: "memory");
  else                     asm volatile("s_waitcnt vmcnt(5)" ::: "memory");
}
__device__ __forceinline__ void wait_zero() {
  asm volatile("s_waitcnt vmcnt(0)" ::: "memory");
}
__device__ __forceinline__ void bar_pin() {
  __builtin_amdgcn_s_barrier();
  __builtin_amdgcn_sched_barrier(0);
}

// chunked XCD swizzle (requires nwg % 8 == 0): consecutive logical ids land
// on the same XCD -> B-panel + L-row L2 locality.
__device__ __forceinline__ int xcd_swz(int bid, int nwg) {
  int cpx = nwg >> 3;
  return (bid & 7) * cpx + (bid >> 3);
}

__device__ __forceinline__ void tile_decode(int bid, int& d, int& t) {
  if (bid < RB_[0]) { d = 0; t = bid; }
  else if (bid < RB_[0] + RB_[1]) { d = 1; t = bid - RB_[0]; }
  else { d = 2; t = bid - RB_[0] - RB_[1]; }
}

// =====================================================================
// prep: xT[c][m] = bf16(x[b][i][m]), c=b*4+i (zero-padded to Mp); zero csums
// =====================================================================
struct PrepArgs {
  const float* x[3];
  unsigned short* xT[3];
  float* zero0; int zero_n;
};

__global__ __launch_bounds__(256) void prep_k(PrepArgs pa) {
  int d, t; tile_decode(blockIdx.x, d, t);
  const int M = MS_[d], Mp = MP_[d];
  const float* x = pa.x[d];
  unsigned short* xT = pa.xT[d];
  const int tid = threadIdx.x;
  const int m0 = t * 64;
  const int ml = tid & 63, cg = tid >> 6;
  const int m = m0 + ml;
  const bool valid = m < M;
#pragma unroll
  for (int it = 0; it < 8; ++it) {
    int c = it * 4 + cg;
    float v = valid ? x[(size_t)c * M + m] : 0.f;
    xT[(size_t)c * Mp + m] = f2bf(v);
  }
  if (blockIdx.x == 0) {
    for (int i = tid; i < pa.zero_n; i += 256) pa.zero0[i] = 0.f;
  }
}

// =====================================================================
// GEMM: P[s][Mp][BN] partials of (L @ Bt^T)  — R3 structure (best measured).
// A: f32 L direct to registers (each wave owns a disjoint 16-row strip,
//    2 named register buffers; OOB rows/k clamp to safe addresses,
//    garbage annihilated by zero-padded B / masked downstream).
// B: bf16 panel via global_load_lds (zero VGPR cost), 4-buffer LDS ring,
//    prefetch distance 2, pre-swizzled source + swizzled read.
// One barrier per K-step, counted vmcnt (never 0 in steady state):
//   per 1-step: loadA=4 ops, stageB=1 (BN=32) or 4 (BN=128).
//   BN=32:  wait 6 drains oldest {B,A} group of 5 from 11.
//   BN=128: wait 12 drains oldest {B,A} group of 8 from 20.
// =====================================================================
struct GemmArgs {
  const float* L[3];
  const unsigned short* B[3];
  float* P[3];
};

template <int BN>
__global__ __launch_bounds__(256, 2) void gemm_k(GemmArgs ga) {
  int bid = xcd_swz(blockIdx.x, (BN == 32) ? NG1 : NG2);
  int d, local;  // longest-first: d1, d2, d0
  if constexpr (BN == 32) {
    if (bid < NB1_[1]) { d = 1; local = bid; }
    else if (bid < NB1_[1] + NB1_[2]) { d = 2; local = bid - NB1_[1]; }
    else { d = 0; local = bid - NB1_[1] - NB1_[2]; }
  } else {
    if (bid < NB2_[1]) { d = 1; local = bid; }
    else if (bid < NB2_[1] + NB2_[2]) { d = 2; local = bid - NB2_[1]; }
    else { d = 0; local = bid - NB2_[1] - NB2_[2]; }
  }

  const int M = MS_[d], Mp = MP_[d], RB = RB_[d];
  const int KS = (BN == 32) ? KS1_[d] : KS2_[d];
  const int r = local % RB, s = local / RB;

  const float* __restrict__ Lp = ga.L[d];
  const unsigned short* __restrict__ Bt = ga.B[d];
  float* __restrict__ Pp = ga.P[d];

  const int m0 = r * 64;
  const int kt0 = s * KS;
  const int nsteps = KS >> 6;  // 4/12/8 (p1) or 8/24/16 (p2) — always even

  __shared__ __align__(16) unsigned short Bl[4][BN * 64];

  const int tid = threadIdx.x;
  const int lane = tid & 63;
  const int wave = tid >> 6;
  const int lr = lane & 15, lk = lane >> 4;
  constexpr int NR = BN / 16;   // accumulator fragments per wave
  constexpr int BI = BN / 32;   // gload_lds insts per thread per stage

  int rowg = m0 + wave * 16 + lr;
  if (rowg > M - 1) rowg = M - 1;  // clamped rows produce garbage; masked later
  const float* __restrict__ pA = Lp + (size_t)rowg * M;

  // B staging source descriptors (pre-swizzled k so LDS dest stays linear)
  const unsigned short* srcB[BI];
#pragma unroll
  for (int j = 0; j < BI; ++j) {
    int colg = (wave * BI + j) * 8 + (lane >> 3);
    int ke = ((lane & 7) * 8) ^ ((colg & 7) << 3);
    srcB[j] = Bt + (size_t)colg * Mp + ke;
  }

  f32x4 acc[NR];
#pragma unroll
  for (int n = 0; n < NR; ++n) acc[n] = (f32x4){0.f, 0.f, 0.f, 0.f};

  auto stageB = [&](int buf, int step) {
    const int kt = kt0 + step * 64;
#pragma unroll
    for (int j = 0; j < BI; ++j)
      gload_lds16(srcB[j] + kt, &Bl[buf][(wave * BI + j) * 512]);
  };
  auto loadA = [&](f32x4 (&ab)[2][2], int step) {
    const int kt = kt0 + step * 64;
#pragma unroll
    for (int kk = 0; kk < 2; ++kk) {
      int k = kt + kk * 32 + lk * 8;
      if (k + 8 > M) k = 0;  // safe addr; B is zero there so product is 0
      const float* p = pA + k;
      ab[kk][0] = *reinterpret_cast<const f32x4*>(p);
      ab[kk][1] = *reinterpret_cast<const f32x4*>(p + 4);
    }
  };
  auto compute = [&](f32x4 (&ab)[2][2], int buf) {
    bf16x8 af[2];
#pragma unroll
    for (int kk = 0; kk < 2; ++kk)
#pragma unroll
      for (int j = 0; j < 4; ++j) {
        af[kk][j] = (__bf16)ab[kk][0][j];
        af[kk][4 + j] = (__bf16)ab[kk][1][j];
      }
    const unsigned short* Bb = &Bl[buf][0];
#pragma unroll
    for (int nr = 0; nr < NR; ++nr) {
      const int col = nr * 16 + lr;
      const int base = col * 64, swz = (col & 7) << 3;
      bf16x8 b0 = *reinterpret_cast<const bf16x8*>(&Bb[base + ((lk * 8) ^ swz)]);
      bf16x8 b1 = *reinterpret_cast<const bf16x8*>(&Bb[base + ((32 + lk * 8) ^ swz)]);
      acc[nr] = __builtin_amdgcn_mfma_f32_16x16x32_bf16(af[0], b0, acc[nr], 0, 0, 0);
      acc[nr] = __builtin_amdgcn_mfma_f32_16x16x32_bf16(af[1], b1, acc[nr], 0, 0, 0);
    }
  };

  f32x4 a0[2][2], a1[2][2];
  // prologue establishes queue: B(0), A(0), B(1), A(1)
  stageB(0, 0);
  loadA(a0, 0);
  stageB(1, 1);
  loadA(a1, 1);

  for (int t = 0; t < nsteps - 2; t += 2) {
    // body t (even): compute a0/buf t
    stageB((t + 2) & 3, t + 2);
    wait_main<BN>();
    bar_pin();
    compute(a0, t & 3);
    loadA(a0, t + 2);
    // body t+1 (odd): compute a1/buf t+1
    stageB((t + 3) & 3, t + 3);
    wait_main<BN>();
    bar_pin();
    compute(a1, (t + 1) & 3);
    loadA(a1, t + 3);
  }
  // body nsteps-2
  wait_tail<BN>();
  bar_pin();
  compute(a0, (nsteps - 2) & 3);
  // body nsteps-1
  wait_zero();
  bar_pin();
  compute(a1, (nsteps - 1) & 3);

  // epilogue: write per-split partials (no atomics)
  const int rowb = m0 + wave * 16 + lk * 4;
#pragma unroll
  for (int nr = 0; nr < NR; ++nr) {
    const int cc = nr * 16 + lr;
#pragma unroll
    for (int j = 0; j < 4; ++j) {
      int rr = rowb + j;
      Pp[((size_t)s * Mp + rr) * BN + cc] = acc[nr][j];
    }
  }
}

// =====================================================================
// epiA: z = leaky(bias + th0*x + th1*Y1) -> bf16 zT (sums 8 partials)
// =====================================================================
struct EpiAArgs {
  const float* part1[3];
  const float* x[3];
  const float* th1[3];
  const float* b1[3];
  unsigned short* zT[3];
};

__global__ __launch_bounds__(256) void epiA_k(EpiAArgs ea) {
  int d, t; tile_decode(blockIdx.x, d, t);
  const int M = MS_[d], Mp = MP_[d];
  const int m0 = t * 64;
  __shared__ float Ys[32 * 66];
  __shared__ float Xs[32 * 66];
  const int tid = threadIdx.x;
  const float* part = ea.part1[d];
  const size_t st = (size_t)Mp * 32;
#pragma unroll
  for (int it = 0; it < 8; ++it) {
    int idx = it * 256 + tid;
    int m = idx >> 5, c = idx & 31;
    size_t base = (size_t)(m0 + m) * 32 + c;
    float ssum = 0.f;
#pragma unroll
    for (int s5 = 0; s5 < 8; ++s5) ssum += part[s5 * st + base];
    Ys[c * 66 + m] = ssum;
  }
  {
    const float* x = ea.x[d];
    int m = tid & 63, cg = tid >> 6;
    bool valid = (m0 + m) < M;
#pragma unroll
    for (int it = 0; it < 8; ++it) {
      int c = it * 4 + cg;
      Xs[c * 66 + m] = valid ? x[(size_t)c * M + m0 + m] : 0.f;
    }
  }
  __syncthreads();
  const float* th = ea.th1[d];
  const float* bias = ea.b1[d];
  unsigned short* zT = ea.zT[d];
  const int m = tid & 63, cog = tid >> 6;
  const bool valid = (m0 + m) < M;
#pragma unroll
  for (int it = 0; it < 32; ++it) {
    int co = it * 4 + cog;
    int o = co & 15, b = co >> 4;
    float a = bias[o];
#pragma unroll
    for (int i = 0; i < 4; ++i) {
      int ci = b * 4 + i;
      a += th[(o * 4 + i) * 2] * Xs[ci * 66 + m] + th[(o * 4 + i) * 2 + 1] * Ys[ci * 66 + m];
    }
    float zz = (a >= 0.f) ? a : 0.01f * a;
    zT[(size_t)co * Mp + m0 + m] = valid ? f2bf(zz) : (unsigned short)0;
  }
}

// =====================================================================
// epiB: out2 = th2_0 * z + th2_1 * Y2 ; column-sums for pooled means
// =====================================================================
struct EpiBArgs {
  const float* part2[3];
  const unsigned short* zT[3];
  const float* th2[3];
  float* out;
  float* csz;  // [3][128]
  float* csy;  // [3][128]
};

__global__ __launch_bounds__(256) void epiB_k(EpiBArgs eb) {
  int d, t; tile_decode(blockIdx.x, d, t);
  const int M = MS_[d], Mp = MP_[d];
  const int m0 = t * 64;
  __shared__ float Ys[128 * 66];
  __shared__ float red[256];
  const int tid = threadIdx.x;
  const float* part = eb.part2[d];
  float csum = 0.f;
#pragma unroll
  for (int it = 0; it < 32; ++it) {
    int idx = it * 256 + tid;
    int m = idx >> 7, c = idx & 127;
    size_t base = (size_t)(m0 + m) * 128 + c;
    size_t st = (size_t)Mp * 128;
    float ssum = part[base] + part[st + base] + part[2 * st + base] + part[3 * st + base];
    Ys[c * 66 + m] = ssum;
    if (m0 + m < M) csum += ssum;  // mask garbage rows (clamped A loads)
  }
  red[tid] = csum;
  __syncthreads();
  if (tid < 128) atomicAdd(&eb.csy[d * 128 + tid], red[tid] + red[tid + 128]);

  const unsigned short* zT = eb.zT[d];
  const float* th = eb.th2[d];
  float* outp = eb.out + OUT_OFF_[d];
  const int m = tid & 63, g = tid >> 6;
  const bool valid = (m0 + m) < M;
#pragma unroll
  for (int bb = 0; bb < 2; ++bb) {
    int b = g * 2 + bb;
    float zv[16], yv[16];
#pragma unroll
    for (int o1 = 0; o1 < 16; ++o1) {
      int c = b * 16 + o1;
      unsigned short raw = zT[(size_t)c * Mp + m0 + m];
      __bf16 bf = *reinterpret_cast<__bf16*>(&raw);
      zv[o1] = (float)bf;
      yv[o1] = Ys[c * 66 + m];
    }
#pragma unroll
    for (int o1 = 0; o1 < 16; ++o1) {
      float v = zv[o1];
#pragma unroll
      for (int off = 32; off > 0; off >>= 1) v += __shfl_xor(v, off, 64);
      if (m == 0) atomicAdd(&eb.csz[d * 128 + b * 16 + o1], v);
    }
#pragma unroll
    for (int o2 = 0; o2 < 32; ++o2) {
      float v = 0.f;
#pragma unroll
      for (int o1 = 0; o1 < 16; ++o1)
        v += th[(o2 * 16 + o1) * 2] * zv[o1] + th[(o2 * 16 + o1) * 2 + 1] * yv[o1];
      if (valid) outp[(size_t)(b * 32 + o2) * M + m0 + m] = v;
    }
  }
}

// =====================================================================
// MLP: pooled from colsums, then 4 affine layers -> logits
// =====================================================================
struct MlpArgs {
  const float* csz; const float* csy;
  const float* th2[3];
  const float* W1; const float* b1;
  const float* W2; const float* b2;
  const float* W3; const float* b3;
  const float* W4; const float* b4;
  float* out;
};

__global__ __launch_bounds__(256) void mlp_k(MlpArgs ma) {
  __shared__ float pl[8][96];
  __shared__ float h1[8][64];
  __shared__ float h2[8][32];
  __shared__ float h3[8][16];
  const int tid = threadIdx.x;
  for (int id = tid; id < 768; id += 256) {
    int d = id >> 8, rem = id & 255, b = rem >> 5, o2 = rem & 31;
    const float* th = ma.th2[d];
    float invM = 1.f / (float)MS_[d];
    float v = 0.f;
    for (int o1 = 0; o1 < 16; ++o1)
      v += th[(o2 * 16 + o1) * 2] * ma.csz[d * 128 + b * 16 + o1] +
           th[(o2 * 16 + o1) * 2 + 1] * ma.csy[d * 128 + b * 16 + o1];
    pl[b][d * 32 + o2] = v * invM;
  }
  __syncthreads();
  for (int id = tid; id < 512; id += 256) {
    int b = id >> 6, j = id & 63;
    float v = ma.b1[j];
    for (int k = 0; k < 96; ++k) v += pl[b][k] * ma.W1[j * 96 + k];
    h1[b][j] = v;
  }
  __syncthreads();
  {
    int b = tid >> 5, j = tid & 31;
    float v = ma.b2[j];
    for (int k = 0; k < 64; ++k) v += h1[b][k] * ma.W2[j * 64 + k];
    h2[b][j] = v;
  }
  __syncthreads();
  if (tid < 128) {
    int b = tid >> 4, j = tid & 15;
    float v = ma.b3[j];
    for (int k = 0; k < 32; ++k) v += h2[b][k] * ma.W3[j * 32 + k];
    h3[b][j] = v;
  }
  __syncthreads();
  if (tid < 16) {
    int b = tid >> 1, j = tid & 1;
    float v = ma.b4[j];
    for (int k = 0; k < 16; ++k) v += h3[b][k] * ma.W4[j * 16 + k];
    ma.out[tid] = v;
  }
}

// =====================================================================
extern "C" void kernel_launch(void* const* d_in, const int* in_sizes, int n_in,
                              void* d_out, int out_size, void* d_ws, size_t ws_size,
                              hipStream_t stream) {
  (void)in_sizes; (void)n_in; (void)out_size; (void)ws_size;
  const float* L[3]   = {(const float*)d_in[0], (const float*)d_in[5], (const float*)d_in[10]};
  const float* x[3]   = {(const float*)d_in[1], (const float*)d_in[6], (const float*)d_in[11]};
  const float* th1[3] = {(const float*)d_in[2], (const float*)d_in[7], (const float*)d_in[12]};
  const float* b1[3]  = {(const float*)d_in[3], (const float*)d_in[8], (const float*)d_in[13]};
  const float* th2[3] = {(const float*)d_in[4], (const float*)d_in[9], (const float*)d_in[14]};
  const float* W1 = (const float*)d_in[15]; const float* bb1 = (const float*)d_in[16];
  const float* W2 = (const float*)d_in[17]; const float* bb2 = (const float*)d_in[18];
  const float* W3 = (const float*)d_in[19]; const float* bb3 = (const float*)d_in[20];
  const float* W4 = (const float*)d_in[21]; const float* bb4 = (const float*)d_in[22];
  float* out = (float*)d_out;

  char* ws = (char*)d_ws;
  size_t off = 0;
  auto alloc = [&](size_t bytes) {
    size_t r = off;
    off = (off + bytes + 255) & ~(size_t)255;
    return r;
  };
  const int MPs[3] = {2048, 6144, 4096};
  unsigned short* xT[3]; unsigned short* zT[3]; float* pb[3];
  for (int d = 0; d < 3; ++d) xT[d] = (unsigned short*)(ws + alloc((size_t)32 * MPs[d] * 2));
  for (int d = 0; d < 3; ++d) zT[d] = (unsigned short*)(ws + alloc((size_t)128 * MPs[d] * 2));
  // p1 (8 x Mp x 32 f32 = Mp*1024B) and p2 (4 x Mp x 128 f32 = Mp*2048B):
  // disjoint lifetimes -> overlaid; alloc the max.
  for (int d = 0; d < 3; ++d) pb[d] = (float*)(ws + alloc((size_t)MPs[d] * 2048));
  float* csz = (float*)(ws + alloc((size_t)3 * 128 * 4));
  float* csy = (float*)(ws + alloc((size_t)3 * 128 * 4));

  PrepArgs pa;
  for (int d = 0; d < 3; ++d) { pa.x[d] = x[d]; pa.xT[d] = xT[d]; }
  pa.zero0 = csz; pa.zero_n = 768;  // csz and csy are contiguous
  prep_k<<<NTILE, 256, 0, stream>>>(pa);

  GemmArgs g1;
  for (int d = 0; d < 3; ++d) { g1.L[d] = L[d]; g1.B[d] = xT[d]; g1.P[d] = pb[d]; }
  gemm_k<32><<<NG1, 256, 0, stream>>>(g1);

  EpiAArgs ea;
  for (int d = 0; d < 3; ++d) {
    ea.part1[d] = pb[d]; ea.x[d] = x[d]; ea.th1[d] = th1[d]; ea.b1[d] = b1[d]; ea.zT[d] = zT[d];
  }
  epiA_k<<<NTILE, 256, 0, stream>>>(ea);

  GemmArgs g2;
  for (int d = 0; d < 3; ++d) { g2.L[d] = L[d]; g2.B[d] = zT[d]; g2.P[d] = pb[d]; }
  gemm_k<128><<<NG2, 256, 0, stream>>>(g2);

  EpiBArgs eb;
  for (int d = 0; d < 3; ++d) { eb.part2[d] = pb[d]; eb.zT[d] = zT[d]; eb.th2[d] = th2[d]; }
  eb.out = out; eb.csz = csz; eb.csy = csy;
  epiB_k<<<NTILE, 256, 0, stream>>>(eb);

  MlpArgs ma;
  ma.csz = csz; ma.csy = csy;
  for (int d = 0; d < 3; ++d) ma.th2[d] = th2[d];
  ma.W1 = W1; ma.b1 = bb1; ma.W2 = W2; ma.b2 = bb2;
  ma.W3 = W3; ma.b3 = bb3; ma.W4 = W4; ma.b4 = bb4;
  ma.out = out;
  mlp_k<<<1, 256, 0, stream>>>(ma);
}

// Round 11
// 192.116 us; speedup vs baseline: 1.3525x; 1.0036x over previous
//
#include <hip/hip_runtime.h>
#include <stdint.h>

typedef __attribute__((ext_vector_type(4))) float f32x4;
typedef __attribute__((ext_vector_type(8))) __bf16 bf16x8;

// ---- fixed problem geometry (from setup_inputs) ----
constexpr int MS_[3] = {2000, 6000, 4000};
constexpr int MP_[3] = {2048, 6144, 4096};  // = 4*KS exactly
constexpr int KS_[3] = {512, 1536, 1024};   // K-chunk per split (S=4), mult of 64
constexpr int RB_[3] = {32, 96, 64};        // row blocks of 64 (Mp/64)
constexpr int NB_[3] = {128, 384, 256};     // RB*S
constexpr int NTILE = 192;                  // sum RB
constexpr int NGEMMB = 768;                 // sum NB
constexpr long long OUT_OFF_[3] = {16, 512016, 2048016};

__device__ __forceinline__ unsigned short f2bf(float f) {
  __bf16 b = (__bf16)f;
  return *reinterpret_cast<unsigned short*>(&b);
}

__device__ __forceinline__ void gload_lds16(const void* g, void* l) {
  __builtin_amdgcn_global_load_lds(
      (const __attribute__((address_space(1))) unsigned int*)g,
      (__attribute__((address_space(3))) unsigned int*)l, 16, 0, 0);
}

template <int BN>
__device__ __forceinline__ void wait_main() {
  if constexpr (BN == 128) asm volatile("s_waitcnt vmcnt(12)" ::: "memory");
  else                     asm volatile("s_waitcnt vmcnt(6)" ::: "memory");
}
template <int BN>
__device__ __forceinline__ void wait_tail() {
  if constexpr (BN == 128) asm volatile("s_waitcnt vmcnt(8)" ::: "memory");
  else                     asm volatile("s_waitcnt vmcnt(5)" ::: "memory");
}
__device__ __forceinline__ void wait_zero() {
  asm volatile("s_waitcnt vmcnt(0)" ::: "memory");
}
__device__ __forceinline__ void bar_pin() {
  __builtin_amdgcn_s_barrier();
  __builtin_amdgcn_sched_barrier(0);
}

__device__ __forceinline__ void tile_decode(int bid, int& d, int& t) {
  if (bid < RB_[0]) { d = 0; t = bid; }
  else if (bid < RB_[0] + RB_[1]) { d = 1; t = bid - RB_[0]; }
  else { d = 2; t = bid - RB_[0] - RB_[1]; }
}

// =====================================================================
// prep: xT[c][m] = bf16(x[b][i][m]), c=b*4+i (zero-padded to Mp); zero csums
// =====================================================================
struct PrepArgs {
  const float* x[3];
  unsigned short* xT[3];
  float* zero0; int zero_n;
};

__global__ __launch_bounds__(256) void prep_k(PrepArgs pa) {
  int d, t; tile_decode(blockIdx.x, d, t);
  const int M = MS_[d], Mp = MP_[d];
  const float* x = pa.x[d];
  unsigned short* xT = pa.xT[d];
  const int tid = threadIdx.x;
  const int m0 = t * 64;
  const int ml = tid & 63, cg = tid >> 6;
  const int m = m0 + ml;
  const bool valid = m < M;
#pragma unroll
  for (int it = 0; it < 8; ++it) {
    int c = it * 4 + cg;
    float v = valid ? x[(size_t)c * M + m] : 0.f;
    xT[(size_t)c * Mp + m] = f2bf(v);
  }
  if (blockIdx.x == 0) {
    for (int i = tid; i < pa.zero_n; i += 256) pa.zero0[i] = 0.f;
  }
}

// =====================================================================
// GEMM: P[s][Mp][BN] partials of (L @ Bt^T).
// A: f32 L direct to registers (each wave owns a disjoint 16-row strip,
//    2-deep named register pipeline; OOB rows/k clamp to safe addresses,
//    garbage is annihilated by zero-padded B).
// B: bf16 panel via global_load_lds (zero VGPR cost), 4-buffer LDS ring,
//    prefetch distance 2, pre-swizzled source + swizzled read.
// One barrier per K-step, counted vmcnt (never 0 in steady state).
// =====================================================================
struct GemmArgs {
  const float* L[3];
  const unsigned short* B[3];
  float* P[3];
};

template <int BN>
__global__ __launch_bounds__(256, 2) void gemm_k(GemmArgs ga) {
  const int bid = blockIdx.x;
  int d, local;  // d=1 blocks first (longest-first scheduling)
  if (bid < NB_[1]) { d = 1; local = bid; }
  else if (bid < NB_[1] + NB_[2]) { d = 2; local = bid - NB_[1]; }
  else { d = 0; local = bid - NB_[1] - NB_[2]; }

  const int M = MS_[d], Mp = MP_[d], KS = KS_[d], RB = RB_[d];
  const int r = local % RB, s = local / RB;

  const float* __restrict__ Lp = ga.L[d];
  const unsigned short* __restrict__ Bt = ga.B[d];
  float* __restrict__ Pp = ga.P[d];

  const int m0 = r * 64;
  const int kt0 = s * KS;
  const int nsteps = KS >> 6;  // 8 / 24 / 16 — always even

  __shared__ __align__(16) unsigned short Bl[4][BN * 64];

  const int tid = threadIdx.x;
  const int lane = tid & 63;
  const int wave = tid >> 6;
  const int lr = lane & 15, lk = lane >> 4;
  constexpr int NR = BN / 16;   // accumulator fragments per wave
  constexpr int BI = BN / 32;   // gload_lds insts per wave per stage

  int rowg = m0 + wave * 16 + lr;
  if (rowg > M - 1) rowg = M - 1;  // clamped rows produce garbage; masked later
  const float* __restrict__ pA = Lp + (size_t)rowg * M;

  // B staging source descriptors (pre-swizzled k so LDS dest stays linear)
  const unsigned short* srcB[BI];
#pragma unroll
  for (int j = 0; j < BI; ++j) {
    int colg = (wave * BI + j) * 8 + (lane >> 3);
    int ke = ((lane & 7) * 8) ^ ((colg & 7) << 3);
    srcB[j] = Bt + (size_t)colg * Mp + ke;
  }

  f32x4 acc[NR];
#pragma unroll
  for (int n = 0; n < NR; ++n) acc[n] = (f32x4){0.f, 0.f, 0.f, 0.f};

  auto stageB = [&](int buf, int step) {
    const int kt = kt0 + step * 64;
#pragma unroll
    for (int j = 0; j < BI; ++j)
      gload_lds16(srcB[j] + kt, &Bl[buf][(wave * BI + j) * 512]);
  };
  auto loadA = [&](f32x4 (&ab)[2][2], int step) {
    const int kt = kt0 + step * 64;
#pragma unroll
    for (int kk = 0; kk < 2; ++kk) {
      int k = kt + kk * 32 + lk * 8;
      if (k + 8 > M) k = 0;  // safe addr; B is zero there so product is 0
      const float* p = pA + k;
      ab[kk][0] = *reinterpret_cast<const f32x4*>(p);
      ab[kk][1] = *reinterpret_cast<const f32x4*>(p + 4);
    }
  };
  auto compute = [&](f32x4 (&ab)[2][2], int buf) {
    bf16x8 af[2];
#pragma unroll
    for (int kk = 0; kk < 2; ++kk)
#pragma unroll
      for (int j = 0; j < 4; ++j) {
        af[kk][j] = (__bf16)ab[kk][0][j];
        af[kk][4 + j] = (__bf16)ab[kk][1][j];
      }
    const unsigned short* Bb = &Bl[buf][0];
#pragma unroll
    for (int nr = 0; nr < NR; ++nr) {
      const int col = nr * 16 + lr;
      const int base = col * 64, swz = (col & 7) << 3;
      bf16x8 b0 = *reinterpret_cast<const bf16x8*>(&Bb[base + ((lk * 8) ^ swz)]);
      bf16x8 b1 = *reinterpret_cast<const bf16x8*>(&Bb[base + ((32 + lk * 8) ^ swz)]);
      acc[nr] = __builtin_amdgcn_mfma_f32_16x16x32_bf16(af[0], b0, acc[nr], 0, 0, 0);
      acc[nr] = __builtin_amdgcn_mfma_f32_16x16x32_bf16(af[1], b1, acc[nr], 0, 0, 0);
    }
  };

  f32x4 a0[2][2], a1[2][2];
  // prologue establishes queue: B(0), A(0), B(1)
  stageB(0, 0);
  loadA(a0, 0);
  stageB(1, 1);

  for (int t = 0; t < nsteps - 2; t += 2) {
    // body t (even): compute a0/buf t
    loadA(a1, t + 1);
    stageB((t + 2) & 3, t + 2);
    wait_main<BN>();
    bar_pin();
    compute(a0, t & 3);
    // body t+1 (odd): compute a1/buf t+1
    loadA(a0, t + 2);
    stageB((t + 3) & 3, t + 3);
    wait_main<BN>();
    bar_pin();
    compute(a1, (t + 1) & 3);
  }
  // body nsteps-2
  loadA(a1, nsteps - 1);
  wait_tail<BN>();
  bar_pin();
  compute(a0, (nsteps - 2) & 3);
  // body nsteps-1
  wait_zero();
  bar_pin();
  compute(a1, (nsteps - 1) & 3);

  // epilogue: write per-split partials (no atomics)
  const int rowb = m0 + wave * 16 + lk * 4;
#pragma unroll
  for (int nr = 0; nr < NR; ++nr) {
    const int cc = nr * 16 + lr;
#pragma unroll
    for (int j = 0; j < 4; ++j) {
      int rr = rowb + j;
      Pp[((size_t)s * Mp + rr) * BN + cc] = acc[nr][j];
    }
  }
}

// =====================================================================
// epiA: z[c=(b*16+o)][m] = leaky(bias[o] + sum_i th0*x + th1*Y1) -> bf16 zT
// =====================================================================
struct EpiAArgs {
  const float* part1[3];
  const float* x[3];
  const float* th1[3];
  const float* b1[3];
  unsigned short* zT[3];
};

__global__ __launch_bounds__(256) void epiA_k(EpiAArgs ea) {
  int d, t; tile_decode(blockIdx.x, d, t);
  const int M = MS_[d], Mp = MP_[d];
  const int m0 = t * 64;
  __shared__ float Ys[32 * 66];
  __shared__ float Xs[32 * 66];
  const int tid = threadIdx.x;
  const float* part = ea.part1[d];
#pragma unroll
  for (int it = 0; it < 8; ++it) {
    int idx = it * 256 + tid;
    int m = idx >> 5, c = idx & 31;
    size_t base = (size_t)(m0 + m) * 32 + c;
    size_t st = (size_t)Mp * 32;
    float ssum = part[base] + part[st + base] + part[2 * st + base] + part[3 * st + base];
    Ys[c * 66 + m] = ssum;
  }
  {
    const float* x = ea.x[d];
    int m = tid & 63, cg = tid >> 6;
    bool valid = (m0 + m) < M;
#pragma unroll
    for (int it = 0; it < 8; ++it) {
      int c = it * 4 + cg;
      Xs[c * 66 + m] = valid ? x[(size_t)c * M + m0 + m] : 0.f;
    }
  }
  __syncthreads();
  const float* th = ea.th1[d];
  const float* bias = ea.b1[d];
  unsigned short* zT = ea.zT[d];
  const int m = tid & 63, cog = tid >> 6;
  const bool valid = (m0 + m) < M;
#pragma unroll
  for (int it = 0; it < 32; ++it) {
    int co = it * 4 + cog;
    int o = co & 15, b = co >> 4;
    float a = bias[o];
#pragma unroll
    for (int i = 0; i < 4; ++i) {
      int ci = b * 4 + i;
      a += th[(o * 4 + i) * 2] * Xs[ci * 66 + m] + th[(o * 4 + i) * 2 + 1] * Ys[ci * 66 + m];
    }
    float zz = (a >= 0.f) ? a : 0.01f * a;
    zT[(size_t)co * Mp + m0 + m] = valid ? f2bf(zz) : (unsigned short)0;
  }
}

// =====================================================================
// epiB: out2 = th2_0 * z + th2_1 * Y2 ; column-sums for pooled means
// =====================================================================
struct EpiBArgs {
  const float* part2[3];
  const unsigned short* zT[3];
  const float* th2[3];
  float* out;
  float* csz;  // [3][128]
  float* csy;  // [3][128]
};

__global__ __launch_bounds__(256) void epiB_k(EpiBArgs eb) {
  int d, t; tile_decode(blockIdx.x, d, t);
  const int M = MS_[d], Mp = MP_[d];
  const int m0 = t * 64;
  __shared__ float Ys[128 * 66];
  __shared__ float red[256];
  const int tid = threadIdx.x;
  const float* part = eb.part2[d];
  float csum = 0.f;
#pragma unroll
  for (int it = 0; it < 32; ++it) {
    int idx = it * 256 + tid;
    int m = idx >> 7, c = idx & 127;
    size_t base = (size_t)(m0 + m) * 128 + c;
    size_t st = (size_t)Mp * 128;
    float ssum = part[base] + part[st + base] + part[2 * st + base] + part[3 * st + base];
    Ys[c * 66 + m] = ssum;
    if (m0 + m < M) csum += ssum;  // mask garbage rows (clamped A loads)
  }
  red[tid] = csum;
  __syncthreads();
  if (tid < 128) atomicAdd(&eb.csy[d * 128 + tid], red[tid] + red[tid + 128]);

  const unsigned short* zT = eb.zT[d];
  const float* th = eb.th2[d];
  float* outp = eb.out + OUT_OFF_[d];
  const int m = tid & 63, g = tid >> 6;
  const bool valid = (m0 + m) < M;
#pragma unroll
  for (int bb = 0; bb < 2; ++bb) {
    int b = g * 2 + bb;
    float zv[16], yv[16];
#pragma unroll
    for (int o1 = 0; o1 < 16; ++o1) {
      int c = b * 16 + o1;
      unsigned short raw = zT[(size_t)c * Mp + m0 + m];
      __bf16 bf = *reinterpret_cast<__bf16*>(&raw);
      zv[o1] = (float)bf;
      yv[o1] = Ys[c * 66 + m];
    }
#pragma unroll
    for (int o1 = 0; o1 < 16; ++o1) {
      float v = zv[o1];
#pragma unroll
      for (int off = 32; off > 0; off >>= 1) v += __shfl_xor(v, off, 64);
      if (m == 0) atomicAdd(&eb.csz[d * 128 + b * 16 + o1], v);
    }
#pragma unroll
    for (int o2 = 0; o2 < 32; ++o2) {
      float v = 0.f;
#pragma unroll
      for (int o1 = 0; o1 < 16; ++o1)
        v += th[(o2 * 16 + o1) * 2] * zv[o1] + th[(o2 * 16 + o1) * 2 + 1] * yv[o1];
      if (valid) outp[(size_t)(b * 32 + o2) * M + m0 + m] = v;
    }
  }
}

// =====================================================================
// MLP: pooled from colsums, then 4 affine layers -> logits
// =====================================================================
struct MlpArgs {
  const float* csz; const float* csy;
  const float* th2[3];
  const float* W1; const float* b1;
  const float* W2; const float* b2;
  const float* W3; const float* b3;
  const float* W4; const float* b4;
  float* out;
};

__global__ __launch_bounds__(256) void mlp_k(MlpArgs ma) {
  __shared__ float pl[8][96];
  __shared__ float h1[8][64];
  __shared__ float h2[8][32];
  __shared__ float h3[8][16];
  const int tid = threadIdx.x;
  for (int id = tid; id < 768; id += 256) {
    int d = id >> 8, rem = id & 255, b = rem >> 5, o2 = rem & 31;
    const float* th = ma.th2[d];
    float invM = 1.f / (float)MS_[d];
    float v = 0.f;
    for (int o1 = 0; o1 < 16; ++o1)
      v += th[(o2 * 16 + o1) * 2] * ma.csz[d * 128 + b * 16 + o1] +
           th[(o2 * 16 + o1) * 2 + 1] * ma.csy[d * 128 + b * 16 + o1];
    pl[b][d * 32 + o2] = v * invM;
  }
  __syncthreads();
  for (int id = tid; id < 512; id += 256) {
    int b = id >> 6, j = id & 63;
    float v = ma.b1[j];
    for (int k = 0; k < 96; ++k) v += pl[b][k] * ma.W1[j * 96 + k];
    h1[b][j] = v;
  }
  __syncthreads();
  {
    int b = tid >> 5, j = tid & 31;
    float v = ma.b2[j];
    for (int k = 0; k < 64; ++k) v += h1[b][k] * ma.W2[j * 64 + k];
    h2[b][j] = v;
  }
  __syncthreads();
  if (tid < 128) {
    int b = tid >> 4, j = tid & 15;
    float v = ma.b3[j];
    for (int k = 0; k < 32; ++k) v += h2[b][k] * ma.W3[j * 32 + k];
    h3[b][j] = v;
  }
  __syncthreads();
  if (tid < 16) {
    int b = tid >> 1, j = tid & 1;
    float v = ma.b4[j];
    for (int k = 0; k < 16; ++k) v += h3[b][k] * ma.W4[j * 16 + k];
    ma.out[tid] = v;
  }
}

// =====================================================================
extern "C" void kernel_launch(void* const* d_in, const int* in_sizes, int n_in,
                              void* d_out, int out_size, void* d_ws, size_t ws_size,
                              hipStream_t stream) {
  (void)in_sizes; (void)n_in; (void)out_size; (void)ws_size;
  const float* L[3]   = {(const float*)d_in[0], (const float*)d_in[5], (const float*)d_in[10]};
  const float* x[3]   = {(const float*)d_in[1], (const float*)d_in[6], (const float*)d_in[11]};
  const float* th1[3] = {(const float*)d_in[2], (const float*)d_in[7], (const float*)d_in[12]};
  const float* b1[3]  = {(const float*)d_in[3], (const float*)d_in[8], (const float*)d_in[13]};
  const float* th2[3] = {(const float*)d_in[4], (const float*)d_in[9], (const float*)d_in[14]};
  const float* W1 = (const float*)d_in[15]; const float* bb1 = (const float*)d_in[16];
  const float* W2 = (const float*)d_in[17]; const float* bb2 = (const float*)d_in[18];
  const float* W3 = (const float*)d_in[19]; const float* bb3 = (const float*)d_in[20];
  const float* W4 = (const float*)d_in[21]; const float* bb4 = (const float*)d_in[22];
  float* out = (float*)d_out;

  char* ws = (char*)d_ws;
  size_t off = 0;
  auto alloc = [&](size_t bytes) {
    size_t r = off;
    off = (off + bytes + 255) & ~(size_t)255;
    return r;
  };
  const int MPs[3] = {2048, 6144, 4096};
  unsigned short* xT[3]; unsigned short* zT[3]; float* p1[3]; float* p2[3];
  for (int d = 0; d < 3; ++d) xT[d] = (unsigned short*)(ws + alloc((size_t)32 * MPs[d] * 2));
  for (int d = 0; d < 3; ++d) zT[d] = (unsigned short*)(ws + alloc((size_t)128 * MPs[d] * 2));
  for (int d = 0; d < 3; ++d) p1[d] = (float*)(ws + alloc((size_t)4 * MPs[d] * 32 * 4));
  for (int d = 0; d < 3; ++d) p2[d] = (float*)(ws + alloc((size_t)4 * MPs[d] * 128 * 4));
  float* csz = (float*)(ws + alloc((size_t)3 * 128 * 4));
  float* csy = (float*)(ws + alloc((size_t)3 * 128 * 4));

  PrepArgs pa;
  for (int d = 0; d < 3; ++d) { pa.x[d] = x[d]; pa.xT[d] = xT[d]; }
  pa.zero0 = csz; pa.zero_n = 768;  // csz and csy are contiguous
  prep_k<<<NTILE, 256, 0, stream>>>(pa);

  GemmArgs g1;
  for (int d = 0; d < 3; ++d) { g1.L[d] = L[d]; g1.B[d] = xT[d]; g1.P[d] = p1[d]; }
  gemm_k<32><<<NGEMMB, 256, 0, stream>>>(g1);

  EpiAArgs ea;
  for (int d = 0; d < 3; ++d) {
    ea.part1[d] = p1[d]; ea.x[d] = x[d]; ea.th1[d] = th1[d]; ea.b1[d] = b1[d]; ea.zT[d] = zT[d];
  }
  epiA_k<<<NTILE, 256, 0, stream>>>(ea);

  GemmArgs g2;
  for (int d = 0; d < 3; ++d) { g2.L[d] = L[d]; g2.B[d] = zT[d]; g2.P[d] = p2[d]; }
  gemm_k<128><<<NGEMMB, 256, 0, stream>>>(g2);

  EpiBArgs eb;
  for (int d = 0; d < 3; ++d) { eb.part2[d] = p2[d]; eb.zT[d] = zT[d]; eb.th2[d] = th2[d]; }
  eb.out = out; eb.csz = csz; eb.csy = csy;
  epiB_k<<<NTILE, 256, 0, stream>>>(eb);

  MlpArgs ma;
  ma.csz = csz; ma.csy = csy;
  for (int d = 0; d < 3; ++d) ma.th2[d] = th2[d];
  ma.W1 = W1; ma.b1 = bb1; ma.W2 = W2; ma.b2 = bb2;
  ma.W3 = W3; ma.b3 = bb3; ma.W4 = W4; ma.b4 = bb4;
  ma.out = out;
  mlp_k<<<1, 256, 0, stream>>>(ma);
}